// Round 1
// baseline (2490.041 us; speedup 1.0000x reference)
//
#include <hip/hip_runtime.h>

// Problem constants (match reference)
#define NUM_USERS   50000
#define NUM_ITEMS   10000
#define NUM_SUPPORT 5
#define INPUT_DIM   512
#define OUTPUT_DIM  500
#define HIDDEN      100      // OUTPUT_DIM / NUM_SUPPORT
#define NNZ         400000

// ---------------------------------------------------------------------------
// Tiled f32 GEMM: C[M,N] = A[M,K] @ B[K,N], all row-major.
// 64x64 tile, 256 threads, 4x4 micro-tile per thread, K-tile 16.
// ---------------------------------------------------------------------------
#define TM 64
#define TN 64
#define TK 16

__global__ __launch_bounds__(256) void gemm_f32(
    const float* __restrict__ A, const float* __restrict__ B,
    float* __restrict__ C, int M, int N, int K)
{
    __shared__ float As[TK][TM + 4];
    __shared__ float Bs[TK][TN + 4];

    const int tid = threadIdx.x;
    const int tx  = tid & 15;       // 0..15 -> 4 cols each
    const int ty  = tid >> 4;       // 0..15 -> 4 rows each
    const int row0 = blockIdx.x * TM;
    const int col0 = blockIdx.y * TN;

    float acc[4][4] = {};

    for (int k0 = 0; k0 < K; k0 += TK) {
        // Load A tile (TM x TK): consecutive tids read 16 consecutive k's per row
        #pragma unroll
        for (int it = 0; it < (TM * TK) / 256; ++it) {
            int idx = tid + it * 256;
            int m  = idx >> 4;          // /TK
            int kk = idx & 15;          // %TK
            int gr = row0 + m;
            As[kk][m] = (gr < M) ? A[(long long)gr * K + (k0 + kk)] : 0.f;
        }
        // Load B tile (TK x TN): consecutive tids read 64 consecutive cols
        #pragma unroll
        for (int it = 0; it < (TK * TN) / 256; ++it) {
            int idx = tid + it * 256;
            int kk = idx >> 6;          // /TN
            int n  = idx & 63;          // %TN
            int gc = col0 + n;
            Bs[kk][n] = (gc < N) ? B[(long long)(k0 + kk) * N + gc] : 0.f;
        }
        __syncthreads();

        #pragma unroll
        for (int kk = 0; kk < TK; ++kk) {
            float a[4], b[4];
            #pragma unroll
            for (int u = 0; u < 4; ++u) a[u] = As[kk][ty * 4 + u];
            #pragma unroll
            for (int v = 0; v < 4; ++v) b[v] = Bs[kk][tx * 4 + v];
            #pragma unroll
            for (int u = 0; u < 4; ++u)
                #pragma unroll
                for (int v = 0; v < 4; ++v)
                    acc[u][v] += a[u] * b[v];
        }
        __syncthreads();
    }

    #pragma unroll
    for (int u = 0; u < 4; ++u) {
        int gr = row0 + ty * 4 + u;
        if (gr >= M) continue;
        #pragma unroll
        for (int v = 0; v < 4; ++v) {
            int gc = col0 + tx * 4 + v;
            if (gc < N) C[(long long)gr * N + gc] = acc[u][v];
        }
    }
}

// ---------------------------------------------------------------------------
// COO scatter: one thread per (support, edge, j).
//   z_u[r, 100i+j] += val * XV[c, 100i+j]
//   z_v[c, 100i+j] += val * XU[r, 100i+j]
// ---------------------------------------------------------------------------
__global__ __launch_bounds__(256) void scatter_edges(
    const float* __restrict__ sup_vals,
    const int*   __restrict__ sup_rows,
    const int*   __restrict__ sup_cols,
    const float* __restrict__ XU,   // [NUM_USERS, OUTPUT_DIM]
    const float* __restrict__ XV,   // [NUM_ITEMS, OUTPUT_DIM]
    float* __restrict__ z_u,        // [NUM_USERS, OUTPUT_DIM]
    float* __restrict__ z_v)        // [NUM_ITEMS, OUTPUT_DIM]
{
    const unsigned t = blockIdx.x * 256u + threadIdx.x;
    const unsigned total = (unsigned)NUM_SUPPORT * NNZ * HIDDEN;  // 2e8
    if (t >= total) return;

    const unsigned j  = t % HIDDEN;
    const unsigned eg = t / HIDDEN;            // global edge id, [0, 5*NNZ)
    const unsigned i  = eg / NNZ;              // support index
    // eg is also the flat index into sup_* arrays ([5, NNZ] row-major)

    const float val = sup_vals[eg];
    const int   r   = sup_rows[eg];
    const int   c   = sup_cols[eg];
    const int   colOff = i * HIDDEN + j;

    atomicAdd(&z_u[(long long)r * OUTPUT_DIM + colOff],
              val * XV[(long long)c * OUTPUT_DIM + colOff]);
    atomicAdd(&z_v[(long long)c * OUTPUT_DIM + colOff],
              val * XU[(long long)r * OUTPUT_DIM + colOff]);
}

// ---------------------------------------------------------------------------
// In-place ReLU, float4
// ---------------------------------------------------------------------------
__global__ __launch_bounds__(256) void relu_inplace(float4* __restrict__ p, int n4)
{
    int t = blockIdx.x * 256 + threadIdx.x;
    if (t >= n4) return;
    float4 v = p[t];
    v.x = v.x > 0.f ? v.x : 0.f;
    v.y = v.y > 0.f ? v.y : 0.f;
    v.z = v.z > 0.f ? v.z : 0.f;
    v.w = v.w > 0.f ? v.w : 0.f;
    p[t] = v;
}

extern "C" void kernel_launch(void* const* d_in, const int* in_sizes, int n_in,
                              void* d_out, int out_size, void* d_ws, size_t ws_size,
                              hipStream_t stream)
{
    const float* x_u      = (const float*)d_in[0];  // [50000, 512]
    const float* x_v      = (const float*)d_in[1];  // [10000, 512]
    const float* W        = (const float*)d_in[2];  // [512, 500]
    const float* sup_vals = (const float*)d_in[3];  // [5, 400000]
    const int*   sup_rows = (const int*)d_in[4];
    const int*   sup_cols = (const int*)d_in[5];

    float* z_u = (float*)d_out;                     // 25,000,000 floats
    float* z_v = z_u + (long long)NUM_USERS * OUTPUT_DIM;  // 5,000,000 floats

    float* XU = (float*)d_ws;                       // 25M floats = 100 MB
    float* XV = XU + (long long)NUM_USERS * OUTPUT_DIM;    // 5M floats = 20 MB

    // Zero accumulators (d_out is re-poisoned 0xAA before every call)
    hipMemsetAsync(d_out, 0, (size_t)out_size * sizeof(float), stream);

    dim3 blk(256);

    // XU = x_u @ W
    gemm_f32<<<dim3((NUM_USERS + TM - 1) / TM, (OUTPUT_DIM + TN - 1) / TN),
               blk, 0, stream>>>(x_u, W, XU, NUM_USERS, OUTPUT_DIM, INPUT_DIM);
    // XV = x_v @ W
    gemm_f32<<<dim3((NUM_ITEMS + TM - 1) / TM, (OUTPUT_DIM + TN - 1) / TN),
               blk, 0, stream>>>(x_v, W, XV, NUM_ITEMS, OUTPUT_DIM, INPUT_DIM);

    // Edge scatter with atomics
    {
        unsigned total = (unsigned)NUM_SUPPORT * NNZ * HIDDEN;  // 200,000,000
        unsigned blocks = (total + 255u) / 256u;
        scatter_edges<<<blocks, blk, 0, stream>>>(sup_vals, sup_rows, sup_cols,
                                                  XU, XV, z_u, z_v);
    }

    // ReLU in place over the whole output (30M floats, divisible by 4)
    {
        int n4 = out_size / 4;
        relu_inplace<<<(n4 + 255) / 256, blk, 0, stream>>>((float4*)d_out, n4);
    }
}

// Round 2
// 1645.824 us; speedup vs baseline: 1.5129x; 1.5129x over previous
//
#include <hip/hip_runtime.h>

// Problem constants (match reference)
#define NUM_USERS   50000
#define NUM_ITEMS   10000
#define NUM_SUPPORT 5
#define INPUT_DIM   512
#define OUTPUT_DIM  500
#define HIDDEN      100      // OUTPUT_DIM / NUM_SUPPORT
#define NNZ         400000
#define NEDGE       (NUM_SUPPORT * NNZ)     // 2,000,000

typedef unsigned int u32;

// ---------------------------------------------------------------------------
// Tiled f32 GEMM: C[M,N] = A[M,K] @ B[K,N], all row-major. (unchanged from R1)
// ---------------------------------------------------------------------------
#define TM 64
#define TN 64
#define TK 16

__global__ __launch_bounds__(256) void gemm_f32(
    const float* __restrict__ A, const float* __restrict__ B,
    float* __restrict__ C, int M, int N, int K)
{
    __shared__ float As[TK][TM + 4];
    __shared__ float Bs[TK][TN + 4];

    const int tid = threadIdx.x;
    const int tx  = tid & 15;
    const int ty  = tid >> 4;
    const int row0 = blockIdx.x * TM;
    const int col0 = blockIdx.y * TN;

    float acc[4][4] = {};

    for (int k0 = 0; k0 < K; k0 += TK) {
        #pragma unroll
        for (int it = 0; it < (TM * TK) / 256; ++it) {
            int idx = tid + it * 256;
            int m  = idx >> 4;
            int kk = idx & 15;
            int gr = row0 + m;
            As[kk][m] = (gr < M) ? A[(long long)gr * K + (k0 + kk)] : 0.f;
        }
        #pragma unroll
        for (int it = 0; it < (TK * TN) / 256; ++it) {
            int idx = tid + it * 256;
            int kk = idx >> 6;
            int n  = idx & 63;
            int gc = col0 + n;
            Bs[kk][n] = (gc < N) ? B[(long long)(k0 + kk) * N + gc] : 0.f;
        }
        __syncthreads();

        #pragma unroll
        for (int kk = 0; kk < TK; ++kk) {
            float a[4], b[4];
            #pragma unroll
            for (int u = 0; u < 4; ++u) a[u] = As[kk][ty * 4 + u];
            #pragma unroll
            for (int v = 0; v < 4; ++v) b[v] = Bs[kk][tx * 4 + v];
            #pragma unroll
            for (int u = 0; u < 4; ++u)
                #pragma unroll
                for (int v = 0; v < 4; ++v)
                    acc[u][v] += a[u] * b[v];
        }
        __syncthreads();
    }

    #pragma unroll
    for (int u = 0; u < 4; ++u) {
        int gr = row0 + ty * 4 + u;
        if (gr >= M) continue;
        #pragma unroll
        for (int v = 0; v < 4; ++v) {
            int gc = col0 + tx * 4 + v;
            if (gc < N) C[(long long)gr * N + gc] = acc[u][v];
        }
    }
}

// ---------------------------------------------------------------------------
// CSR build: histogram -> exclusive scan -> stable-ish scatter
// ---------------------------------------------------------------------------
__global__ __launch_bounds__(256) void hist_edges(
    const int* __restrict__ rows, const int* __restrict__ cols,
    u32* __restrict__ cnt_u, u32* __restrict__ cnt_v)
{
    unsigned eg = blockIdx.x * 256u + threadIdx.x;
    if (eg >= NEDGE) return;
    unsigned i = eg / NNZ;
    atomicAdd(&cnt_u[i * NUM_USERS + rows[eg]], 1u);
    atomicAdd(&cnt_v[i * NUM_ITEMS + cols[eg]], 1u);
}

// Block-level exclusive scan: 1024 elements/block (256 thr x 4), partial sums out.
__global__ __launch_bounds__(256) void scan1(u32* __restrict__ data, int n,
                                             u32* __restrict__ partials)
{
    __shared__ u32 sh[256];
    int t = threadIdx.x;
    int base = blockIdx.x * 1024 + t * 4;
    u32 x[4];
    #pragma unroll
    for (int k = 0; k < 4; ++k) {
        int idx = base + k;
        x[k] = (idx < n) ? data[idx] : 0u;
    }
    u32 tsum = x[0] + x[1] + x[2] + x[3];
    sh[t] = tsum;
    __syncthreads();
    for (int off = 1; off < 256; off <<= 1) {
        u32 v = (t >= off) ? sh[t - off] : 0u;
        __syncthreads();
        sh[t] += v;
        __syncthreads();
    }
    u32 run = (t > 0) ? sh[t - 1] : 0u;
    if (t == 255) partials[blockIdx.x] = sh[255];
    #pragma unroll
    for (int k = 0; k < 4; ++k) {
        int idx = base + k;
        if (idx < n) data[idx] = run;
        run += x[k];
    }
}

// Single-block exclusive scan of the partials (n <= 256).
__global__ __launch_bounds__(256) void scan_partials(u32* __restrict__ partials, int n)
{
    __shared__ u32 sh[256];
    int t = threadIdx.x;
    u32 x = (t < n) ? partials[t] : 0u;
    sh[t] = x;
    __syncthreads();
    for (int off = 1; off < 256; off <<= 1) {
        u32 v = (t >= off) ? sh[t - off] : 0u;
        __syncthreads();
        sh[t] += v;
        __syncthreads();
    }
    if (t < n) partials[t] = (t > 0) ? sh[t - 1] : 0u;
}

__global__ __launch_bounds__(256) void scan_add(u32* __restrict__ data, int n,
                                                const u32* __restrict__ partials)
{
    int idx = blockIdx.x * 256 + threadIdx.x;
    if (idx < n) data[idx] += partials[idx >> 10];
}

__global__ __launch_bounds__(256) void sort_edges(
    const float* __restrict__ vals,
    const int*   __restrict__ rows, const int* __restrict__ cols,
    u32* __restrict__ cur_u, u32* __restrict__ cur_v,
    float* __restrict__ sv_u, int* __restrict__ sc_u,
    float* __restrict__ sv_v, int* __restrict__ sr_v)
{
    unsigned eg = blockIdx.x * 256u + threadIdx.x;
    if (eg >= NEDGE) return;
    unsigned i = eg / NNZ;
    float v = vals[eg];
    int r = rows[eg];
    int c = cols[eg];
    u32 p = atomicAdd(&cur_u[i * NUM_USERS + r], 1u);
    sv_u[p] = v;
    sc_u[p] = c;
    u32 q = atomicAdd(&cur_v[i * NUM_ITEMS + c], 1u);
    sv_v[q] = v;
    sr_v[q] = r;
}

// ---------------------------------------------------------------------------
// CSR SpMM: one wave per (support, output-row). 100-wide accumulator in regs
// (lane l holds cols l and 64+l). Fused ReLU. Every output element written.
// ---------------------------------------------------------------------------
__global__ __launch_bounds__(256) void spmm_csr(
    const u32* __restrict__ ptr,     // start offsets [NUM_SUPPORT*nrows]
    const u32* __restrict__ endp,    // end offsets (cursor after scatter)
    const float* __restrict__ svals, // sorted edge values
    const int*   __restrict__ sidx,  // sorted gather indices
    const float* __restrict__ X,     // dense source [nsrc, OUTPUT_DIM]
    float* __restrict__ Z,           // output [nrows, OUTPUT_DIM]
    int nrows)
{
    int wave = (int)((blockIdx.x * 256u + threadIdx.x) >> 6);
    int lane = threadIdx.x & 63;
    if (wave >= NUM_SUPPORT * nrows) return;
    int i = wave / nrows;       // support
    int r = wave % nrows;       // output row
    const int cbase = i * HIDDEN;

    u32 s = ptr[wave], e = endp[wave];
    float a0 = 0.f, a1 = 0.f;
    for (u32 k = s; k < e; ++k) {
        float v = svals[k];
        int g = sidx[k];
        const float* x = X + (long long)g * OUTPUT_DIM + cbase;
        a0 += v * x[lane];
        if (lane < HIDDEN - 64) a1 += v * x[64 + lane];
    }
    float* out = Z + (long long)r * OUTPUT_DIM + cbase;
    out[lane] = a0 > 0.f ? a0 : 0.f;
    if (lane < HIDDEN - 64) out[64 + lane] = a1 > 0.f ? a1 : 0.f;
}

// ---------------------------------------------------------------------------
// Fallback path (R1): COO atomic scatter + relu (used only if ws too small)
// ---------------------------------------------------------------------------
__global__ __launch_bounds__(256) void scatter_edges(
    const float* __restrict__ sup_vals,
    const int*   __restrict__ sup_rows,
    const int*   __restrict__ sup_cols,
    const float* __restrict__ XU,
    const float* __restrict__ XV,
    float* __restrict__ z_u,
    float* __restrict__ z_v)
{
    const unsigned t = blockIdx.x * 256u + threadIdx.x;
    const unsigned total = (unsigned)NEDGE * HIDDEN;
    if (t >= total) return;
    const unsigned j  = t % HIDDEN;
    const unsigned eg = t / HIDDEN;
    const unsigned i  = eg / NNZ;
    const float val = sup_vals[eg];
    const int   r   = sup_rows[eg];
    const int   c   = sup_cols[eg];
    const int   colOff = i * HIDDEN + j;
    atomicAdd(&z_u[(long long)r * OUTPUT_DIM + colOff],
              val * XV[(long long)c * OUTPUT_DIM + colOff]);
    atomicAdd(&z_v[(long long)c * OUTPUT_DIM + colOff],
              val * XU[(long long)r * OUTPUT_DIM + colOff]);
}

__global__ __launch_bounds__(256) void relu_inplace(float4* __restrict__ p, int n4)
{
    int t = blockIdx.x * 256 + threadIdx.x;
    if (t >= n4) return;
    float4 v = p[t];
    v.x = v.x > 0.f ? v.x : 0.f;
    v.y = v.y > 0.f ? v.y : 0.f;
    v.z = v.z > 0.f ? v.z : 0.f;
    v.w = v.w > 0.f ? v.w : 0.f;
    p[t] = v;
}

extern "C" void kernel_launch(void* const* d_in, const int* in_sizes, int n_in,
                              void* d_out, int out_size, void* d_ws, size_t ws_size,
                              hipStream_t stream)
{
    const float* x_u      = (const float*)d_in[0];
    const float* x_v      = (const float*)d_in[1];
    const float* W        = (const float*)d_in[2];
    const float* sup_vals = (const float*)d_in[3];
    const int*   sup_rows = (const int*)d_in[4];
    const int*   sup_cols = (const int*)d_in[5];

    float* z_u = (float*)d_out;
    float* z_v = z_u + (long long)NUM_USERS * OUTPUT_DIM;

    // ---- workspace layout ----
    const long long NU = (long long)NUM_USERS * OUTPUT_DIM;   // 25M
    const long long NV = (long long)NUM_ITEMS * OUTPUT_DIM;   //  5M
    float* XU = (float*)d_ws;
    float* XV = XU + NU;
    u32* row_ptr_u = (u32*)(XV + NV);            // [5*50000]
    u32* cur_u     = row_ptr_u + NUM_SUPPORT * NUM_USERS;
    u32* col_ptr_v = cur_u     + NUM_SUPPORT * NUM_USERS;
    u32* cur_v     = col_ptr_v + NUM_SUPPORT * NUM_ITEMS;
    float* sv_u = (float*)(cur_v + NUM_SUPPORT * NUM_ITEMS);  // [2M]
    int*   sc_u = (int*)(sv_u + NEDGE);
    float* sv_v = (float*)(sc_u + NEDGE);
    int*   sr_v = (int*)(sv_v + NEDGE);
    u32*   partials = (u32*)(sr_v + NEDGE);                    // [1024]
    size_t needed = ((char*)(partials + 1024)) - ((char*)d_ws);

    dim3 blk(256);

    // Dense GEMMs: XU = x_u @ W, XV = x_v @ W
    gemm_f32<<<dim3((NUM_USERS + TM - 1) / TM, (OUTPUT_DIM + TN - 1) / TN),
               blk, 0, stream>>>(x_u, W, XU, NUM_USERS, OUTPUT_DIM, INPUT_DIM);
    gemm_f32<<<dim3((NUM_ITEMS + TM - 1) / TM, (OUTPUT_DIM + TN - 1) / TN),
               blk, 0, stream>>>(x_v, W, XV, NUM_ITEMS, OUTPUT_DIM, INPUT_DIM);

    if (ws_size >= needed) {
        // ---- CSR path: no output atomics ----
        const int NRU = NUM_SUPPORT * NUM_USERS;  // 250000
        const int NRV = NUM_SUPPORT * NUM_ITEMS;  //  50000

        // zero counts (row_ptr_u..cur_v are contiguous)
        hipMemsetAsync(row_ptr_u, 0,
                       (size_t)(2 * NRU + 2 * NRV) * sizeof(u32), stream);

        hist_edges<<<(NEDGE + 255) / 256, blk, 0, stream>>>(
            sup_rows, sup_cols, row_ptr_u, col_ptr_v);

        // exclusive scan of counts -> row pointers (in place)
        {
            int nbU = (NRU + 1023) / 1024;   // 245
            scan1<<<nbU, blk, 0, stream>>>(row_ptr_u, NRU, partials);
            scan_partials<<<1, blk, 0, stream>>>(partials, nbU);
            scan_add<<<(NRU + 255) / 256, blk, 0, stream>>>(row_ptr_u, NRU, partials);

            int nbV = (NRV + 1023) / 1024;   // 49
            scan1<<<nbV, blk, 0, stream>>>(col_ptr_v, NRV, partials);
            scan_partials<<<1, blk, 0, stream>>>(partials, nbV);
            scan_add<<<(NRV + 255) / 256, blk, 0, stream>>>(col_ptr_v, NRV, partials);
        }

        hipMemcpyAsync(cur_u, row_ptr_u, (size_t)NRU * sizeof(u32),
                       hipMemcpyDeviceToDevice, stream);
        hipMemcpyAsync(cur_v, col_ptr_v, (size_t)NRV * sizeof(u32),
                       hipMemcpyDeviceToDevice, stream);

        sort_edges<<<(NEDGE + 255) / 256, blk, 0, stream>>>(
            sup_vals, sup_rows, sup_cols, cur_u, cur_v,
            sv_u, sc_u, sv_v, sr_v);

        // SpMM, fused ReLU, every output element written exactly once.
        // after sort_edges, cur_* hold END offsets.
        spmm_csr<<<(NRU * 64 + 255) / 256, blk, 0, stream>>>(
            row_ptr_u, cur_u, sv_u, sc_u, XV, z_u, NUM_USERS);
        spmm_csr<<<(NRV * 64 + 255) / 256, blk, 0, stream>>>(
            col_ptr_v, cur_v, sv_v, sr_v, XU, z_v, NUM_ITEMS);
    } else {
        // ---- fallback: atomic COO path ----
        hipMemsetAsync(d_out, 0, (size_t)out_size * sizeof(float), stream);
        unsigned total = (unsigned)NEDGE * HIDDEN;
        scatter_edges<<<(total + 255u) / 256u, blk, 0, stream>>>(
            sup_vals, sup_rows, sup_cols, XU, XV, z_u, z_v);
        int n4 = out_size / 4;
        relu_inplace<<<(n4 + 255) / 256, blk, 0, stream>>>((float4*)d_out, n4);
    }
}

// Round 3
// 1247.716 us; speedup vs baseline: 1.9957x; 1.3191x over previous
//
#include <hip/hip_runtime.h>

// Problem constants (match reference)
#define NUM_USERS   50000
#define NUM_ITEMS   10000
#define NUM_SUPPORT 5
#define INPUT_DIM   512      // K
#define OUTPUT_DIM  500
#define NPAD        512      // padded output-dim stride for XU/XV
#define HIDDEN      100      // OUTPUT_DIM / NUM_SUPPORT
#define NNZ         400000
#define NEDGE       (NUM_SUPPORT * NNZ)     // 2,000,000

typedef unsigned int u32;
typedef unsigned short ushort_t;
typedef __attribute__((ext_vector_type(4))) float f32x4;
typedef __attribute__((ext_vector_type(8))) short bf16x8;   // 8 bf16 in 4 VGPRs

// async global->LDS, 16B per lane. LDS side must be wave-uniform-base + lane*16.
#define GLDS(g, l) __builtin_amdgcn_global_load_lds( \
    (const __attribute__((address_space(1))) unsigned int*)(g), \
    (__attribute__((address_space(3))) unsigned int*)(l), 16, 0, 0)

__device__ inline ushort_t bf16_rne(float f) {
    u32 u = __float_as_uint(f);
    u32 r = (u + 0x7FFFu + ((u >> 16) & 1u)) >> 16;
    return (ushort_t)r;
}

// ---------------------------------------------------------------------------
// f32 -> bf16 conversion, 4 elems/thread
// ---------------------------------------------------------------------------
__global__ __launch_bounds__(256) void cvt_bf16(
    const float4* __restrict__ in, ushort4* __restrict__ out, int n4)
{
    int t = blockIdx.x * 256 + threadIdx.x;
    if (t >= n4) return;
    float4 v = in[t];
    ushort4 o;
    o.x = bf16_rne(v.x); o.y = bf16_rne(v.y);
    o.z = bf16_rne(v.z); o.w = bf16_rne(v.w);
    out[t] = o;
}

// WbT[n][k] = W[k][n] (bf16), n padded 500->512 with zeros. 512x512.
__global__ __launch_bounds__(256) void make_WbT(
    const float* __restrict__ W, ushort_t* __restrict__ WbT)
{
    int t = blockIdx.x * 256 + threadIdx.x;   // 262144 threads
    int n = t >> 9, k = t & 511;
    float v = (n < OUTPUT_DIM) ? W[k * OUTPUT_DIM + n] : 0.f;
    WbT[t] = bf16_rne(v);
}

// ---------------------------------------------------------------------------
// MFMA bf16 GEMM: C[M][512] = A[M][512](bf16) @ BT[512][512](bf16)^T
// 128x128 tile, BK=32, 256 thr (4 waves, each 64x64 = 4x4 tiles of 16x16x32).
// A and BT both stored row-major along K -> identical staging/fragment paths.
// ---------------------------------------------------------------------------
#define BM 128
#define BN 128
#define BK 32

__global__ __launch_bounds__(256) void gemm_mfma_bf16(
    const ushort_t* __restrict__ A,    // [M][512] bf16
    const ushort_t* __restrict__ BT,   // [512][512] bf16 (BT[n][k])
    float* __restrict__ C,             // [M][512] f32 (all 512 cols written)
    int M)
{
    const int K = INPUT_DIM;
    __shared__ ushort_t As[BM * BK];   // [m][k], 64B rows
    __shared__ ushort_t Bs[BN * BK];   // [n][k], 64B rows

    const int tid  = threadIdx.x;
    const int wave = tid >> 6;
    const int lane = tid & 63;
    const int quad = lane >> 4;
    const int lr   = lane & 15;
    const int m0 = blockIdx.x * BM;
    const int n0 = blockIdx.y * BN;
    const int wm = (wave >> 1) * 64;   // wave's 64x64 sub-tile
    const int wn = (wave & 1) * 64;

    f32x4 acc[4][4] = {};

    for (int k0 = 0; k0 < K; k0 += BK) {
        #pragma unroll
        for (int h = 0; h < 2; ++h) {
            int o   = tid * 16 + h * 4096;     // LDS byte offset
            int row = o >> 6;                  // tile row (64B = 32 bf16/row)
            int byt = o & 63;
            int gr  = m0 + row; if (gr >= M) gr = M - 1;   // clamp (masked at store)
            GLDS((const char*)A + ((long long)gr * K + k0) * 2 + byt, (char*)As + o);
        }
        #pragma unroll
        for (int h = 0; h < 2; ++h) {
            int o   = tid * 16 + h * 4096;
            int row = o >> 6;
            int byt = o & 63;
            GLDS((const char*)BT + ((long long)(n0 + row) * K + k0) * 2 + byt, (char*)Bs + o);
        }
        asm volatile("s_waitcnt vmcnt(0)" ::: "memory");
        __syncthreads();

        bf16x8 af[4], bfr[4];
        #pragma unroll
        for (int tm = 0; tm < 4; ++tm)
            af[tm] = *(const bf16x8*)(As + (wm + tm * 16 + lr) * BK + quad * 8);
        #pragma unroll
        for (int tn = 0; tn < 4; ++tn)
            bfr[tn] = *(const bf16x8*)(Bs + (wn + tn * 16 + lr) * BK + quad * 8);
        #pragma unroll
        for (int tm = 0; tm < 4; ++tm)
            #pragma unroll
            for (int tn = 0; tn < 4; ++tn)
                acc[tm][tn] = __builtin_amdgcn_mfma_f32_16x16x32_bf16(
                    af[tm], bfr[tn], acc[tm][tn], 0, 0, 0);
        __syncthreads();
    }

    // epilogue: C/D layout col=lane&15, row=quad*4+reg
    #pragma unroll
    for (int tm = 0; tm < 4; ++tm) {
        int rbase = m0 + wm + tm * 16 + quad * 4;
        #pragma unroll
        for (int tn = 0; tn < 4; ++tn) {
            int col = n0 + wn + tn * 16 + lr;
            #pragma unroll
            for (int g = 0; g < 4; ++g) {
                int row = rbase + g;
                if (row < M) C[(long long)row * NPAD + col] = acc[tm][tn][g];
            }
        }
    }
}

// ---------------------------------------------------------------------------
// Fallback f32 GEMM (R2), with ldc. C[m*ldc+n].
// ---------------------------------------------------------------------------
#define TM 64
#define TN 64
#define TK 16

__global__ __launch_bounds__(256) void gemm_f32(
    const float* __restrict__ A, const float* __restrict__ B,
    float* __restrict__ C, int M, int N, int K, int ldc)
{
    __shared__ float Asl[TK][TM + 4];
    __shared__ float Bsl[TK][TN + 4];
    const int tid = threadIdx.x;
    const int tx  = tid & 15;
    const int ty  = tid >> 4;
    const int row0 = blockIdx.x * TM;
    const int col0 = blockIdx.y * TN;
    float acc[4][4] = {};
    for (int k0 = 0; k0 < K; k0 += TK) {
        #pragma unroll
        for (int it = 0; it < (TM * TK) / 256; ++it) {
            int idx = tid + it * 256;
            int m = idx >> 4, kk = idx & 15, gr = row0 + m;
            Asl[kk][m] = (gr < M) ? A[(long long)gr * K + (k0 + kk)] : 0.f;
        }
        #pragma unroll
        for (int it = 0; it < (TK * TN) / 256; ++it) {
            int idx = tid + it * 256;
            int kk = idx >> 6, n = idx & 63, gc = col0 + n;
            Bsl[kk][n] = (gc < N) ? B[(long long)(k0 + kk) * N + gc] : 0.f;
        }
        __syncthreads();
        #pragma unroll
        for (int kk = 0; kk < TK; ++kk) {
            float a[4], b[4];
            #pragma unroll
            for (int u = 0; u < 4; ++u) a[u] = Asl[kk][ty * 4 + u];
            #pragma unroll
            for (int v = 0; v < 4; ++v) b[v] = Bsl[kk][tx * 4 + v];
            #pragma unroll
            for (int u = 0; u < 4; ++u)
                #pragma unroll
                for (int v = 0; v < 4; ++v)
                    acc[u][v] += a[u] * b[v];
        }
        __syncthreads();
    }
    #pragma unroll
    for (int u = 0; u < 4; ++u) {
        int gr = row0 + ty * 4 + u;
        if (gr >= M) continue;
        #pragma unroll
        for (int v = 0; v < 4; ++v) {
            int gc = col0 + tx * 4 + v;
            if (gc < N) C[(long long)gr * ldc + gc] = acc[u][v];
        }
    }
}

// ---------------------------------------------------------------------------
// CSR build
// ---------------------------------------------------------------------------
__global__ __launch_bounds__(256) void hist_edges(
    const int* __restrict__ rows, const int* __restrict__ cols,
    u32* __restrict__ cnt_u, u32* __restrict__ cnt_v)
{
    unsigned eg = blockIdx.x * 256u + threadIdx.x;
    if (eg >= NEDGE) return;
    unsigned i = eg / NNZ;
    atomicAdd(&cnt_u[i * NUM_USERS + rows[eg]], 1u);
    atomicAdd(&cnt_v[i * NUM_ITEMS + cols[eg]], 1u);
}

__global__ __launch_bounds__(256) void scan1(u32* __restrict__ data, int n,
                                             u32* __restrict__ partials)
{
    __shared__ u32 sh[256];
    int t = threadIdx.x;
    int base = blockIdx.x * 1024 + t * 4;
    u32 x[4];
    #pragma unroll
    for (int k = 0; k < 4; ++k) {
        int idx = base + k;
        x[k] = (idx < n) ? data[idx] : 0u;
    }
    u32 tsum = x[0] + x[1] + x[2] + x[3];
    sh[t] = tsum;
    __syncthreads();
    for (int off = 1; off < 256; off <<= 1) {
        u32 v = (t >= off) ? sh[t - off] : 0u;
        __syncthreads();
        sh[t] += v;
        __syncthreads();
    }
    u32 run = (t > 0) ? sh[t - 1] : 0u;
    if (t == 255) partials[blockIdx.x] = sh[255];
    #pragma unroll
    for (int k = 0; k < 4; ++k) {
        int idx = base + k;
        if (idx < n) data[idx] = run;
        run += x[k];
    }
}

__global__ __launch_bounds__(256) void scan_partials(u32* __restrict__ partials, int n)
{
    __shared__ u32 sh[256];
    int t = threadIdx.x;
    u32 x = (t < n) ? partials[t] : 0u;
    sh[t] = x;
    __syncthreads();
    for (int off = 1; off < 256; off <<= 1) {
        u32 v = (t >= off) ? sh[t - off] : 0u;
        __syncthreads();
        sh[t] += v;
        __syncthreads();
    }
    if (t < n) partials[t] = (t > 0) ? sh[t - 1] : 0u;
}

__global__ __launch_bounds__(256) void scan_add(u32* __restrict__ data, int n,
                                                const u32* __restrict__ partials)
{
    int idx = blockIdx.x * 256 + threadIdx.x;
    if (idx < n) data[idx] += partials[idx >> 10];
}

// scatter edges into CSR slots; packed {val_bits, gather_idx} per edge.
__global__ __launch_bounds__(256) void sort_edges(
    const float* __restrict__ vals,
    const int*   __restrict__ rows, const int* __restrict__ cols,
    u32* __restrict__ cur_u, u32* __restrict__ cur_v,
    uint2* __restrict__ eu, uint2* __restrict__ ev)
{
    unsigned eg = blockIdx.x * 256u + threadIdx.x;
    if (eg >= NEDGE) return;
    unsigned i = eg / NNZ;
    u32 vb = __float_as_uint(vals[eg]);
    int r = rows[eg];
    int c = cols[eg];
    u32 p = atomicAdd(&cur_u[i * NUM_USERS + r], 1u);
    eu[p] = make_uint2(vb, (u32)c);
    u32 q = atomicAdd(&cur_v[i * NUM_ITEMS + c], 1u);
    ev[q] = make_uint2(vb, (u32)r);
}

// ---------------------------------------------------------------------------
// CSR SpMM: one wave per (support, output-row); lanes 0..49 hold 2 cols each.
// X has stride NPAD=512. Fused ReLU; every output element written once.
// ---------------------------------------------------------------------------
__global__ __launch_bounds__(256) void spmm_csr2(
    const u32* __restrict__ ptr, const u32* __restrict__ endp,
    const uint2* __restrict__ edges,
    const float* __restrict__ X,     // [nsrc][NPAD]
    float* __restrict__ Z,           // [nrows][OUTPUT_DIM]
    int nrows)
{
    int wv   = (int)((blockIdx.x * 256u + threadIdx.x) >> 6);
    int lane = threadIdx.x & 63;
    if (wv >= NUM_SUPPORT * nrows) return;
    int i = wv / nrows;
    int r = wv % nrows;
    const int cbase = i * HIDDEN;

    u32 s = ptr[wv], e = endp[wv];
    float ax = 0.f, ay = 0.f;
    for (u32 k = s; k < e; ++k) {
        uint2 p = edges[k];                       // wave-uniform load
        float v = __uint_as_float(p.x);
        const float* xrow = X + (long long)p.y * NPAD + cbase;
        if (lane < 50) {
            float2 xv = *(const float2*)(xrow + 2 * lane);
            ax += v * xv.x;
            ay += v * xv.y;
        }
    }
    if (lane < 50) {
        float* o = Z + (long long)r * OUTPUT_DIM + cbase + 2 * lane;
        o[0] = ax > 0.f ? ax : 0.f;
        o[1] = ay > 0.f ? ay : 0.f;
    }
}

// ---------------------------------------------------------------------------
// Last-resort fallback: COO atomic scatter + relu (X stride = NPAD)
// ---------------------------------------------------------------------------
__global__ __launch_bounds__(256) void scatter_edges(
    const float* __restrict__ sup_vals,
    const int*   __restrict__ sup_rows,
    const int*   __restrict__ sup_cols,
    const float* __restrict__ XU, const float* __restrict__ XV,
    float* __restrict__ z_u, float* __restrict__ z_v)
{
    const unsigned t = blockIdx.x * 256u + threadIdx.x;
    const unsigned total = (unsigned)NEDGE * HIDDEN;
    if (t >= total) return;
    const unsigned j  = t % HIDDEN;
    const unsigned eg = t / HIDDEN;
    const unsigned i  = eg / NNZ;
    const float val = sup_vals[eg];
    const int   r   = sup_rows[eg];
    const int   c   = sup_cols[eg];
    const int   colOff = i * HIDDEN + j;
    atomicAdd(&z_u[(long long)r * OUTPUT_DIM + colOff],
              val * XV[(long long)c * NPAD + colOff]);
    atomicAdd(&z_v[(long long)c * OUTPUT_DIM + colOff],
              val * XU[(long long)r * NPAD + colOff]);
}

__global__ __launch_bounds__(256) void relu_inplace(float4* __restrict__ p, int n4)
{
    int t = blockIdx.x * 256 + threadIdx.x;
    if (t >= n4) return;
    float4 v = p[t];
    v.x = v.x > 0.f ? v.x : 0.f;
    v.y = v.y > 0.f ? v.y : 0.f;
    v.z = v.z > 0.f ? v.z : 0.f;
    v.w = v.w > 0.f ? v.w : 0.f;
    p[t] = v;
}

extern "C" void kernel_launch(void* const* d_in, const int* in_sizes, int n_in,
                              void* d_out, int out_size, void* d_ws, size_t ws_size,
                              hipStream_t stream)
{
    const float* x_u      = (const float*)d_in[0];
    const float* x_v      = (const float*)d_in[1];
    const float* W        = (const float*)d_in[2];
    const float* sup_vals = (const float*)d_in[3];
    const int*   sup_rows = (const int*)d_in[4];
    const int*   sup_cols = (const int*)d_in[5];

    float* z_u = (float*)d_out;
    float* z_v = z_u + (long long)NUM_USERS * OUTPUT_DIM;

    // ---- workspace layout (bf16 buffers last so CSR-only path needs less) ----
    const long long NUP = (long long)NUM_USERS * NPAD;   // 25.6M floats
    const long long NVP = (long long)NUM_ITEMS * NPAD;   //  5.12M floats
    const int NRU = NUM_SUPPORT * NUM_USERS;  // 250000
    const int NRV = NUM_SUPPORT * NUM_ITEMS;  //  50000

    float* XU = (float*)d_ws;
    float* XV = XU + NUP;
    u32* row_ptr_u = (u32*)(XV + NVP);
    u32* cur_u     = row_ptr_u + NRU;
    u32* col_ptr_v = cur_u + NRU;
    u32* cur_v     = col_ptr_v + NRV;
    uint2* eu = (uint2*)(cur_v + NRV);
    uint2* ev = eu + NEDGE;
    u32* partials = (u32*)(ev + NEDGE);       // [1024]
    ushort_t* xu_b = (ushort_t*)(partials + 1024);
    ushort_t* xv_b = xu_b + NUP;
    ushort_t* WbT  = xv_b + NVP;
    size_t need_csr  = ((char*)xu_b) - ((char*)d_ws);
    size_t need_full = ((char*)(WbT + 512 * 512)) - ((char*)d_ws);
    size_t need_min  = ((char*)row_ptr_u) - ((char*)d_ws);

    dim3 blk(256);
    const bool full = (ws_size >= need_full);
    const bool csr  = (ws_size >= need_csr);

    // ---- dense projections ----
    if (full) {
        cvt_bf16<<<(int)((NUP / 4 + 255) / 256), blk, 0, stream>>>(
            (const float4*)x_u, (ushort4*)xu_b, (int)(NUP / 4));
        cvt_bf16<<<(int)((NVP / 4 + 255) / 256), blk, 0, stream>>>(
            (const float4*)x_v, (ushort4*)xv_b, (int)(NVP / 4));
        make_WbT<<<(512 * 512) / 256, blk, 0, stream>>>(W, WbT);
        gemm_mfma_bf16<<<dim3((NUM_USERS + BM - 1) / BM, NPAD / BN), blk, 0, stream>>>(
            xu_b, WbT, XU, NUM_USERS);
        gemm_mfma_bf16<<<dim3((NUM_ITEMS + BM - 1) / BM, NPAD / BN), blk, 0, stream>>>(
            xv_b, WbT, XV, NUM_ITEMS);
    } else {
        gemm_f32<<<dim3((NUM_USERS + TM - 1) / TM, (OUTPUT_DIM + TN - 1) / TN),
                   blk, 0, stream>>>(x_u, W, XU, NUM_USERS, OUTPUT_DIM, INPUT_DIM, NPAD);
        gemm_f32<<<dim3((NUM_ITEMS + TM - 1) / TM, (OUTPUT_DIM + TN - 1) / TN),
                   blk, 0, stream>>>(x_v, W, XV, NUM_ITEMS, OUTPUT_DIM, INPUT_DIM, NPAD);
    }

    if (csr) {
        // ---- CSR path: no output atomics ----
        hipMemsetAsync(row_ptr_u, 0, (size_t)(2 * NRU + 2 * NRV) * sizeof(u32), stream);
        hist_edges<<<(NEDGE + 255) / 256, blk, 0, stream>>>(
            sup_rows, sup_cols, row_ptr_u, col_ptr_v);
        {
            int nbU = (NRU + 1023) / 1024;
            scan1<<<nbU, blk, 0, stream>>>(row_ptr_u, NRU, partials);
            scan_partials<<<1, blk, 0, stream>>>(partials, nbU);
            scan_add<<<(NRU + 255) / 256, blk, 0, stream>>>(row_ptr_u, NRU, partials);
            int nbV = (NRV + 1023) / 1024;
            scan1<<<nbV, blk, 0, stream>>>(col_ptr_v, NRV, partials);
            scan_partials<<<1, blk, 0, stream>>>(partials, nbV);
            scan_add<<<(NRV + 255) / 256, blk, 0, stream>>>(col_ptr_v, NRV, partials);
        }
        hipMemcpyAsync(cur_u, row_ptr_u, (size_t)NRU * sizeof(u32),
                       hipMemcpyDeviceToDevice, stream);
        hipMemcpyAsync(cur_v, col_ptr_v, (size_t)NRV * sizeof(u32),
                       hipMemcpyDeviceToDevice, stream);
        sort_edges<<<(NEDGE + 255) / 256, blk, 0, stream>>>(
            sup_vals, sup_rows, sup_cols, cur_u, cur_v, eu, ev);
        spmm_csr2<<<(NRU * 64 + 255) / 256, blk, 0, stream>>>(
            row_ptr_u, cur_u, eu, XV, z_u, NUM_USERS);
        spmm_csr2<<<(NRV * 64 + 255) / 256, blk, 0, stream>>>(
            col_ptr_v, cur_v, ev, XU, z_v, NUM_ITEMS);
    } else {
        // ---- atomic fallback ----
        (void)need_min;
        hipMemsetAsync(d_out, 0, (size_t)out_size * sizeof(float), stream);
        unsigned total = (unsigned)NEDGE * HIDDEN;
        scatter_edges<<<(total + 255u) / 256u, blk, 0, stream>>>(
            sup_vals, sup_rows, sup_cols, XU, XV, z_u, z_v);
        int n4 = out_size / 4;
        relu_inplace<<<(n4 + 255) / 256, blk, 0, stream>>>((float4*)d_out, n4);
    }
}

// Round 4
// 1194.996 us; speedup vs baseline: 2.0837x; 1.0441x over previous
//
#include <hip/hip_runtime.h>

// Problem constants (match reference)
#define NUM_USERS   50000
#define NUM_ITEMS   10000
#define NUM_SUPPORT 5
#define INPUT_DIM   512      // K
#define OUTPUT_DIM  500
#define NPAD        512      // padded output-dim stride for XU/XV
#define HIDDEN      100      // OUTPUT_DIM / NUM_SUPPORT
#define NNZ         400000
#define NEDGE       (NUM_SUPPORT * NNZ)     // 2,000,000

typedef unsigned int u32;
typedef unsigned short ushort_t;
typedef __attribute__((ext_vector_type(4))) float f32x4;
typedef __attribute__((ext_vector_type(8))) short bf16x8;   // 8 bf16 in 4 VGPRs

// async global->LDS, 16B per lane. LDS side must be wave-uniform base + lane*16.
#define GLDS(g, l) __builtin_amdgcn_global_load_lds( \
    (const __attribute__((address_space(1))) unsigned int*)(g), \
    (__attribute__((address_space(3))) unsigned int*)(l), 16, 0, 0)

__device__ inline ushort_t bf16_rne(float f) {
    u32 u = __float_as_uint(f);
    u32 r = (u + 0x7FFFu + ((u >> 16) & 1u)) >> 16;
    return (ushort_t)r;
}
__device__ inline float bf16_lo_f32(u32 w) { return __uint_as_float(w << 16); }
__device__ inline float bf16_hi_f32(u32 w) { return __uint_as_float(w & 0xFFFF0000u); }

// ---------------------------------------------------------------------------
// f32 -> bf16 conversion, 4 elems/thread
// ---------------------------------------------------------------------------
__global__ __launch_bounds__(256) void cvt_bf16(
    const float4* __restrict__ in, ushort4* __restrict__ out, int n4)
{
    int t = blockIdx.x * 256 + threadIdx.x;
    if (t >= n4) return;
    float4 v = in[t];
    ushort4 o;
    o.x = bf16_rne(v.x); o.y = bf16_rne(v.y);
    o.z = bf16_rne(v.z); o.w = bf16_rne(v.w);
    out[t] = o;
}

// WbT[n][k] = W[k][n] (bf16), n padded 500->512 with zeros. 512x512.
__global__ __launch_bounds__(256) void make_WbT(
    const float* __restrict__ W, ushort_t* __restrict__ WbT)
{
    int t = blockIdx.x * 256 + threadIdx.x;
    int n = t >> 9, k = t & 511;
    float v = (n < OUTPUT_DIM) ? W[k * OUTPUT_DIM + n] : 0.f;
    WbT[t] = bf16_rne(v);
}

// ---------------------------------------------------------------------------
// MFMA bf16 GEMM: C[M][512](bf16) = A[M][512](bf16) @ BT[512][512](bf16)^T
// 128x128 tile, BK=32, 256 thr (4 waves, each 64x64 = 4x4 tiles of 16x16x32).
// Epilogue writes bf16 (halves write traffic; spmm gathers bf16).
// ---------------------------------------------------------------------------
#define BM 128
#define BN 128
#define BK 32

__global__ __launch_bounds__(256) void gemm_mfma_bf16(
    const ushort_t* __restrict__ A,    // [M][512] bf16
    const ushort_t* __restrict__ BT,   // [512][512] bf16 (BT[n][k])
    ushort_t* __restrict__ C,          // [M][512] bf16
    int M)
{
    const int K = INPUT_DIM;
    __shared__ ushort_t As[BM * BK];   // [m][k], 64B rows
    __shared__ ushort_t Bs[BN * BK];   // [n][k], 64B rows

    const int tid  = threadIdx.x;
    const int wave = tid >> 6;
    const int lane = tid & 63;
    const int quad = lane >> 4;
    const int lr   = lane & 15;
    const int m0 = blockIdx.x * BM;
    const int n0 = blockIdx.y * BN;
    const int wm = (wave >> 1) * 64;
    const int wn = (wave & 1) * 64;

    f32x4 acc[4][4] = {};

    for (int k0 = 0; k0 < K; k0 += BK) {
        #pragma unroll
        for (int h = 0; h < 2; ++h) {
            int o   = tid * 16 + h * 4096;
            int row = o >> 6;
            int byt = o & 63;
            int gr  = m0 + row; if (gr >= M) gr = M - 1;   // clamp (masked at store)
            GLDS((const char*)A + ((long long)gr * K + k0) * 2 + byt, (char*)As + o);
        }
        #pragma unroll
        for (int h = 0; h < 2; ++h) {
            int o   = tid * 16 + h * 4096;
            int row = o >> 6;
            int byt = o & 63;
            GLDS((const char*)BT + ((long long)(n0 + row) * K + k0) * 2 + byt, (char*)Bs + o);
        }
        asm volatile("s_waitcnt vmcnt(0)" ::: "memory");
        __syncthreads();

        bf16x8 af[4], bfr[4];
        #pragma unroll
        for (int tm = 0; tm < 4; ++tm)
            af[tm] = *(const bf16x8*)(As + (wm + tm * 16 + lr) * BK + quad * 8);
        #pragma unroll
        for (int tn = 0; tn < 4; ++tn)
            bfr[tn] = *(const bf16x8*)(Bs + (wn + tn * 16 + lr) * BK + quad * 8);
        #pragma unroll
        for (int tm = 0; tm < 4; ++tm)
            #pragma unroll
            for (int tn = 0; tn < 4; ++tn)
                acc[tm][tn] = __builtin_amdgcn_mfma_f32_16x16x32_bf16(
                    af[tm], bfr[tn], acc[tm][tn], 0, 0, 0);
        __syncthreads();
    }

    // epilogue: C/D layout col=lane&15, row=quad*4+reg
    #pragma unroll
    for (int tm = 0; tm < 4; ++tm) {
        int rbase = m0 + wm + tm * 16 + quad * 4;
        #pragma unroll
        for (int tn = 0; tn < 4; ++tn) {
            int col = n0 + wn + tn * 16 + lr;
            #pragma unroll
            for (int g = 0; g < 4; ++g) {
                int row = rbase + g;
                if (row < M) C[(long long)row * NPAD + col] = bf16_rne(acc[tm][tn][g]);
            }
        }
    }
}

// ---------------------------------------------------------------------------
// CSR build: histogram -> exclusive scan -> permutation scatter (4B payload)
// ---------------------------------------------------------------------------
__global__ __launch_bounds__(256) void hist_edges(
    const int* __restrict__ rows, const int* __restrict__ cols,
    u32* __restrict__ cnt_u, u32* __restrict__ cnt_v)
{
    unsigned eg = blockIdx.x * 256u + threadIdx.x;
    if (eg >= NEDGE) return;
    unsigned i = eg / NNZ;
    atomicAdd(&cnt_u[i * NUM_USERS + rows[eg]], 1u);
    atomicAdd(&cnt_v[i * NUM_ITEMS + cols[eg]], 1u);
}

__global__ __launch_bounds__(256) void scan1(u32* __restrict__ data, int n,
                                             u32* __restrict__ partials)
{
    __shared__ u32 sh[256];
    int t = threadIdx.x;
    int base = blockIdx.x * 1024 + t * 4;
    u32 x[4];
    #pragma unroll
    for (int k = 0; k < 4; ++k) {
        int idx = base + k;
        x[k] = (idx < n) ? data[idx] : 0u;
    }
    u32 tsum = x[0] + x[1] + x[2] + x[3];
    sh[t] = tsum;
    __syncthreads();
    for (int off = 1; off < 256; off <<= 1) {
        u32 v = (t >= off) ? sh[t - off] : 0u;
        __syncthreads();
        sh[t] += v;
        __syncthreads();
    }
    u32 run = (t > 0) ? sh[t - 1] : 0u;
    if (t == 255) partials[blockIdx.x] = sh[255];
    #pragma unroll
    for (int k = 0; k < 4; ++k) {
        int idx = base + k;
        if (idx < n) data[idx] = run;
        run += x[k];
    }
}

__global__ __launch_bounds__(256) void scan_partials(u32* __restrict__ partials, int n)
{
    __shared__ u32 sh[256];
    int t = threadIdx.x;
    u32 x = (t < n) ? partials[t] : 0u;
    sh[t] = x;
    __syncthreads();
    for (int off = 1; off < 256; off <<= 1) {
        u32 v = (t >= off) ? sh[t - off] : 0u;
        __syncthreads();
        sh[t] += v;
        __syncthreads();
    }
    if (t < n) partials[t] = (t > 0) ? sh[t - 1] : 0u;
}

__global__ __launch_bounds__(256) void scan_add(u32* __restrict__ data, int n,
                                                const u32* __restrict__ partials)
{
    int idx = blockIdx.x * 256 + threadIdx.x;
    if (idx < n) data[idx] += partials[idx >> 10];
}

// scatter only the edge id (4B) into CSR slots — halves random-write traffic.
__global__ __launch_bounds__(256) void sort_edges(
    const int* __restrict__ rows, const int* __restrict__ cols,
    u32* __restrict__ cur_u, u32* __restrict__ cur_v,
    u32* __restrict__ perm_u, u32* __restrict__ perm_v)
{
    unsigned eg = blockIdx.x * 256u + threadIdx.x;
    if (eg >= NEDGE) return;
    unsigned i = eg / NNZ;
    int r = rows[eg];
    int c = cols[eg];
    u32 p = atomicAdd(&cur_u[i * NUM_USERS + r], 1u);
    perm_u[p] = eg;
    u32 q = atomicAdd(&cur_v[i * NUM_ITEMS + c], 1u);
    perm_v[q] = eg;
}

// ---------------------------------------------------------------------------
// Permutation SpMM: one wave per (support, output-row).
// lanes 0..49 each own 2 cols; gathers are bf16 (u32 = 2 elems). Fused ReLU.
// ---------------------------------------------------------------------------
__global__ __launch_bounds__(256) void spmm_perm(
    const u32* __restrict__ ptr, const u32* __restrict__ endp,
    const u32* __restrict__ perm,
    const float* __restrict__ vals,   // [NEDGE] flat
    const int*   __restrict__ gidx,   // [NEDGE] flat gather index
    const ushort_t* __restrict__ X,   // [nsrc][NPAD] bf16
    float* __restrict__ Z,            // [nrows][OUTPUT_DIM] f32
    int nrows)
{
    int wv   = (int)((blockIdx.x * 256u + threadIdx.x) >> 6);
    int lane = threadIdx.x & 63;
    if (wv >= NUM_SUPPORT * nrows) return;
    int i = wv / nrows;
    int r = wv % nrows;
    const int cbase = i * HIDDEN;

    u32 s = ptr[wv], e = endp[wv];
    float ax = 0.f, ay = 0.f;
    u32 k = s;
    // unroll-2 so the two edges' random loads overlap
    for (; k + 1 < e; k += 2) {
        u32 e0 = perm[k], e1 = perm[k + 1];
        float v0 = vals[e0], v1 = vals[e1];
        int g0 = gidx[e0], g1 = gidx[e1];
        const ushort_t* x0 = X + (long long)g0 * NPAD + cbase;
        const ushort_t* x1 = X + (long long)g1 * NPAD + cbase;
        if (lane < 50) {
            u32 w0 = *(const u32*)(x0 + 2 * lane);
            u32 w1 = *(const u32*)(x1 + 2 * lane);
            ax += v0 * bf16_lo_f32(w0) + v1 * bf16_lo_f32(w1);
            ay += v0 * bf16_hi_f32(w0) + v1 * bf16_hi_f32(w1);
        }
    }
    if (k < e) {
        u32 e0 = perm[k];
        float v0 = vals[e0];
        int g0 = gidx[e0];
        const ushort_t* x0 = X + (long long)g0 * NPAD + cbase;
        if (lane < 50) {
            u32 w0 = *(const u32*)(x0 + 2 * lane);
            ax += v0 * bf16_lo_f32(w0);
            ay += v0 * bf16_hi_f32(w0);
        }
    }
    if (lane < 50) {
        float2 o;
        o.x = ax > 0.f ? ax : 0.f;
        o.y = ay > 0.f ? ay : 0.f;
        *(float2*)(Z + (long long)r * OUTPUT_DIM + cbase + 2 * lane) = o;
    }
}

// ---------------------------------------------------------------------------
// Fallback path: f32 GEMM + COO atomic scatter (only if ws too small)
// ---------------------------------------------------------------------------
#define TM 64
#define TN 64
#define TK 16

__global__ __launch_bounds__(256) void gemm_f32(
    const float* __restrict__ A, const float* __restrict__ B,
    float* __restrict__ C, int M, int N, int K, int ldc)
{
    __shared__ float Asl[TK][TM + 4];
    __shared__ float Bsl[TK][TN + 4];
    const int tid = threadIdx.x;
    const int tx  = tid & 15;
    const int ty  = tid >> 4;
    const int row0 = blockIdx.x * TM;
    const int col0 = blockIdx.y * TN;
    float acc[4][4] = {};
    for (int k0 = 0; k0 < K; k0 += TK) {
        #pragma unroll
        for (int it = 0; it < (TM * TK) / 256; ++it) {
            int idx = tid + it * 256;
            int m = idx >> 4, kk = idx & 15, gr = row0 + m;
            Asl[kk][m] = (gr < M) ? A[(long long)gr * K + (k0 + kk)] : 0.f;
        }
        #pragma unroll
        for (int it = 0; it < (TK * TN) / 256; ++it) {
            int idx = tid + it * 256;
            int kk = idx >> 6, n = idx & 63, gc = col0 + n;
            Bsl[kk][n] = (gc < N) ? B[(long long)(k0 + kk) * N + gc] : 0.f;
        }
        __syncthreads();
        #pragma unroll
        for (int kk = 0; kk < TK; ++kk) {
            float a[4], b[4];
            #pragma unroll
            for (int u = 0; u < 4; ++u) a[u] = Asl[kk][ty * 4 + u];
            #pragma unroll
            for (int v = 0; v < 4; ++v) b[v] = Bsl[kk][tx * 4 + v];
            #pragma unroll
            for (int u = 0; u < 4; ++u)
                #pragma unroll
                for (int v = 0; v < 4; ++v)
                    acc[u][v] += a[u] * b[v];
        }
        __syncthreads();
    }
    #pragma unroll
    for (int u = 0; u < 4; ++u) {
        int gr = row0 + ty * 4 + u;
        if (gr >= M) continue;
        #pragma unroll
        for (int v = 0; v < 4; ++v) {
            int gc = col0 + tx * 4 + v;
            if (gc < N) C[(long long)gr * ldc + gc] = acc[u][v];
        }
    }
}

__global__ __launch_bounds__(256) void scatter_edges(
    const float* __restrict__ sup_vals,
    const int*   __restrict__ sup_rows,
    const int*   __restrict__ sup_cols,
    const float* __restrict__ XU, const float* __restrict__ XV,
    float* __restrict__ z_u, float* __restrict__ z_v)
{
    const unsigned t = blockIdx.x * 256u + threadIdx.x;
    const unsigned total = (unsigned)NEDGE * HIDDEN;
    if (t >= total) return;
    const unsigned j  = t % HIDDEN;
    const unsigned eg = t / HIDDEN;
    const unsigned i  = eg / NNZ;
    const float val = sup_vals[eg];
    const int   r   = sup_rows[eg];
    const int   c   = sup_cols[eg];
    const int   colOff = i * HIDDEN + j;
    atomicAdd(&z_u[(long long)r * OUTPUT_DIM + colOff],
              val * XV[(long long)c * NPAD + colOff]);
    atomicAdd(&z_v[(long long)c * OUTPUT_DIM + colOff],
              val * XU[(long long)r * NPAD + colOff]);
}

__global__ __launch_bounds__(256) void relu_inplace(float4* __restrict__ p, int n4)
{
    int t = blockIdx.x * 256 + threadIdx.x;
    if (t >= n4) return;
    float4 v = p[t];
    v.x = v.x > 0.f ? v.x : 0.f;
    v.y = v.y > 0.f ? v.y : 0.f;
    v.z = v.z > 0.f ? v.z : 0.f;
    v.w = v.w > 0.f ? v.w : 0.f;
    p[t] = v;
}

extern "C" void kernel_launch(void* const* d_in, const int* in_sizes, int n_in,
                              void* d_out, int out_size, void* d_ws, size_t ws_size,
                              hipStream_t stream)
{
    const float* x_u      = (const float*)d_in[0];
    const float* x_v      = (const float*)d_in[1];
    const float* W        = (const float*)d_in[2];
    const float* sup_vals = (const float*)d_in[3];
    const int*   sup_rows = (const int*)d_in[4];
    const int*   sup_cols = (const int*)d_in[5];

    float* z_u = (float*)d_out;
    float* z_v = z_u + (long long)NUM_USERS * OUTPUT_DIM;

    const long long NU = (long long)NUM_USERS * NPAD;   // 25.6M elems
    const long long NV = (long long)NUM_ITEMS * NPAD;   //  5.12M elems
    const int NRU = NUM_SUPPORT * NUM_USERS;  // 250000
    const int NRV = NUM_SUPPORT * NUM_ITEMS;  //  50000

    // ---- full-path workspace layout (all-bf16 dense tensors) ----
    ushort_t* XUb   = (ushort_t*)d_ws;        // gemm out, bf16 [50000][512]
    ushort_t* XVb   = XUb + NU;               // gemm out, bf16 [10000][512]
    ushort_t* xu_in = XVb + NV;               // bf16(x_u)
    ushort_t* xv_in = xu_in + NU;             // bf16(x_v)
    ushort_t* WbT   = xv_in + NV;             // bf16 W^T padded [512][512]
    u32* row_ptr_u  = (u32*)(WbT + 512 * 512);
    u32* cur_u      = row_ptr_u + NRU;
    u32* col_ptr_v  = cur_u + NRU;
    u32* cur_v      = col_ptr_v + NRV;
    u32* perm_u     = cur_v + NRV;            // [NEDGE]
    u32* perm_v     = perm_u + NEDGE;         // [NEDGE]
    u32* partials   = perm_v + NEDGE;         // [1024]
    size_t need_full = ((char*)(partials + 1024)) - ((char*)d_ws);

    dim3 blk(256);

    if (ws_size >= need_full) {
        // ---- dense projections (bf16 MFMA) ----
        cvt_bf16<<<(int)((NU / 4 + 255) / 256), blk, 0, stream>>>(
            (const float4*)x_u, (ushort4*)xu_in, (int)(NU / 4));
        cvt_bf16<<<(int)((NV / 4 + 255) / 256), blk, 0, stream>>>(
            (const float4*)x_v, (ushort4*)xv_in, (int)(NV / 4));
        make_WbT<<<(512 * 512) / 256, blk, 0, stream>>>(W, WbT);
        gemm_mfma_bf16<<<dim3((NUM_USERS + BM - 1) / BM, NPAD / BN), blk, 0, stream>>>(
            xu_in, WbT, XUb, NUM_USERS);
        gemm_mfma_bf16<<<dim3((NUM_ITEMS + BM - 1) / BM, NPAD / BN), blk, 0, stream>>>(
            xv_in, WbT, XVb, NUM_ITEMS);

        // ---- CSR build ----
        hipMemsetAsync(row_ptr_u, 0, (size_t)(2 * NRU + 2 * NRV) * sizeof(u32), stream);
        hist_edges<<<(NEDGE + 255) / 256, blk, 0, stream>>>(
            sup_rows, sup_cols, row_ptr_u, col_ptr_v);
        {
            int nbU = (NRU + 1023) / 1024;
            scan1<<<nbU, blk, 0, stream>>>(row_ptr_u, NRU, partials);
            scan_partials<<<1, blk, 0, stream>>>(partials, nbU);
            scan_add<<<(NRU + 255) / 256, blk, 0, stream>>>(row_ptr_u, NRU, partials);
            int nbV = (NRV + 1023) / 1024;
            scan1<<<nbV, blk, 0, stream>>>(col_ptr_v, NRV, partials);
            scan_partials<<<1, blk, 0, stream>>>(partials, nbV);
            scan_add<<<(NRV + 255) / 256, blk, 0, stream>>>(col_ptr_v, NRV, partials);
        }
        hipMemcpyAsync(cur_u, row_ptr_u, (size_t)NRU * sizeof(u32),
                       hipMemcpyDeviceToDevice, stream);
        hipMemcpyAsync(cur_v, col_ptr_v, (size_t)NRV * sizeof(u32),
                       hipMemcpyDeviceToDevice, stream);
        sort_edges<<<(NEDGE + 255) / 256, blk, 0, stream>>>(
            sup_rows, sup_cols, cur_u, cur_v, perm_u, perm_v);

        // ---- SpMM (fused ReLU) ----
        spmm_perm<<<(NRU * 64 + 255) / 256, blk, 0, stream>>>(
            row_ptr_u, cur_u, perm_u, sup_vals, sup_cols, XVb, z_u, NUM_USERS);
        spmm_perm<<<(NRV * 64 + 255) / 256, blk, 0, stream>>>(
            col_ptr_v, cur_v, perm_v, sup_vals, sup_rows, XUb, z_v, NUM_ITEMS);
    } else {
        // ---- fallback: f32 GEMM + atomic scatter ----
        float* XU = (float*)d_ws;
        float* XV = XU + NU;
        gemm_f32<<<dim3((NUM_USERS + TM - 1) / TM, (OUTPUT_DIM + TN - 1) / TN),
                   blk, 0, stream>>>(x_u, W, XU, NUM_USERS, OUTPUT_DIM, INPUT_DIM, NPAD);
        gemm_f32<<<dim3((NUM_ITEMS + TM - 1) / TM, (OUTPUT_DIM + TN - 1) / TN),
                   blk, 0, stream>>>(x_v, W, XV, NUM_ITEMS, OUTPUT_DIM, INPUT_DIM, NPAD);
        hipMemsetAsync(d_out, 0, (size_t)out_size * sizeof(float), stream);
        unsigned total = (unsigned)NEDGE * HIDDEN;
        scatter_edges<<<(total + 255u) / 256u, blk, 0, stream>>>(
            sup_vals, sup_rows, sup_cols, XU, XV, z_u, z_v);
        int n4 = out_size / 4;
        relu_inplace<<<(n4 + 255) / 256, blk, 0, stream>>>((float4*)d_out, n4);
    }
}